// Round 18
// baseline (6449.046 us; speedup 1.0000x reference)
//
#include <hip/hip_runtime.h>
#include <stdint.h>

typedef unsigned short u16;
typedef short short8 __attribute__((ext_vector_type(8)));
typedef float f32x4 __attribute__((ext_vector_type(4)));
typedef int i32x4 __attribute__((ext_vector_type(4)));
typedef unsigned long long u64;

#define NT 512
#define NH 1024
#define G4H 4096
#define HS_ELEMS 33554432ull   // 64*512*1024

static __device__ __forceinline__ u16 f2bf(float f){
  union { float f; unsigned u; } v; v.f = f;
  unsigned r = v.u + 0x7fffu + ((v.u >> 16) & 1u);   // RNE
  return (u16)(r >> 16);
}
static __device__ __forceinline__ float bf2f(u16 s){
  union { unsigned u; float f; } v; v.u = ((unsigned)s) << 16;
  return v.f;
}

// ---------------- fp32 -> bf16 bulk convert ----------------
__global__ void cvt_kernel(const float* __restrict__ in, u16* __restrict__ out, int n8){
  int i = blockIdx.x*blockDim.x + threadIdx.x;
  int stride = gridDim.x*blockDim.x;
  for (; i < n8; i += stride){
    const float4* p = (const float4*)in;
    float4 a = p[2*i], b = p[2*i+1];
    short8 o;
    o[0]=(short)f2bf(a.x); o[1]=(short)f2bf(a.y); o[2]=(short)f2bf(a.z); o[3]=(short)f2bf(a.w);
    o[4]=(short)f2bf(b.x); o[5]=(short)f2bf(b.y); o[6]=(short)f2bf(b.z); o[7]=(short)f2bf(b.w);
    ((short8*)out)[i] = o;
  }
}

// ---------------- init h ring buffer + counters ----------------
__global__ void init_kernel(unsigned* __restrict__ hx, int* __restrict__ cnt){
  int i = blockIdx.x*blockDim.x + threadIdx.x;
  int stride = gridDim.x*blockDim.x;
  for (int k = i; k < 131072; k += stride) hx[k] = 0u;   // 512 KiB of bf16 zeros
  if (i < 256) cnt[i] = 0;
}

// ---------------- phase 1: xg = x @ w_ih^T + b  (bf16 MFMA, m97-style) ----------------
__global__ __launch_bounds__(256) void gemm_xg(
    const u16* __restrict__ A,     // x bf16 [32768][1024]
    const u16* __restrict__ Bw,    // w_ih bf16 [4096][1024]  (B^T layout)
    const float* __restrict__ bias,
    u16* __restrict__ C)           // xg bf16 [32768][4096]
{
  __shared__ u16 lA[128*64];
  __shared__ u16 lB[128*64];
  const int tid = threadIdx.x, lane = tid & 63, w = tid >> 6;
  int bid = blockIdx.x;
  int swz = (bid & 7)*1024 + (bid >> 3);     // XCD swizzle (8192 % 8 == 0, bijective)
  const int brow = swz >> 5;                 // 0..255
  const int bcol = swz & 31;                 // 0..31
  const int wr = (w >> 1)*64, wc = (w & 1)*64;
  f32x4 acc[4][4] = {};

  const int rA0 = brow*128 + w*32;
  const int rB0 = bcol*128 + w*32;
  for (int kt = 0; kt < 1024; kt += 64){
    const u16* gA = A  + (size_t)(rA0 + (lane>>3))*1024 + kt + (lane&7)*8;
    const u16* gB = Bw + (size_t)(rB0 + (lane>>3))*1024 + kt + (lane&7)*8;
#pragma unroll
    for (int c = 0; c < 4; c++){
      __builtin_amdgcn_global_load_lds(
        (const __attribute__((address_space(1))) void*)(gA + (size_t)c*8*1024),
        (__attribute__((address_space(3))) void*)&lA[(w*32 + c*8)*64], 16, 0, 0);
      __builtin_amdgcn_global_load_lds(
        (const __attribute__((address_space(1))) void*)(gB + (size_t)c*8*1024),
        (__attribute__((address_space(3))) void*)&lB[(w*32 + c*8)*64], 16, 0, 0);
    }
    __syncthreads();
#pragma unroll
    for (int kk = 0; kk < 2; kk++){
      short8 fa[4], fb[4];
#pragma unroll
      for (int i = 0; i < 4; i++){
        fa[i] = *(const short8*)&lA[(wr + i*16 + (lane&15))*64 + kk*32 + (lane>>4)*8];
        fb[i] = *(const short8*)&lB[(wc + i*16 + (lane&15))*64 + kk*32 + (lane>>4)*8];
      }
#pragma unroll
      for (int i = 0; i < 4; i++)
#pragma unroll
        for (int jj = 0; jj < 4; jj++)
          acc[i][jj] = __builtin_amdgcn_mfma_f32_16x16x32_bf16(fa[i], fb[jj], acc[i][jj], 0,0,0);
    }
    __syncthreads();
  }
  const int mb = brow*128 + wr + ((lane>>4)<<2);
  const int nb = bcol*128 + wc + (lane&15);
#pragma unroll
  for (int jj = 0; jj < 4; jj++){
    const int n = nb + jj*16;
    const float bv = bias[n];
#pragma unroll
    for (int i = 0; i < 4; i++){
#pragma unroll
      for (int reg = 0; reg < 4; reg++){
        int m = mb + i*16 + reg;
        C[(size_t)m*G4H + n] = f2bf(acc[i][jj][reg] + bv);
      }
    }
  }
}

// ---------------- phase 2: persistent recurrence (R14 protocol, 16 WGs/group) ----------------
// Grid 64 x 1024 threads = 4 batch-groups x 16 col-slice WGs (64 h-cols each,
// 16 waves). vs R14's 64 WGs/group: 4x fewer signals per step, straggler pool
// max-of-16 not max-of-64, publish-ack aggregated in one intra-WG barrier,
// 4x less L3 stage traffic. Protocol ordering BYTE-IDENTICAL to R14/R17
// (PASSED, 3.36ms): every-WG leader poll -> barrier -> sc1 stage -> LDS ->
// barrier -> MFMA -> publish -> barrier(ack) -> signal -> deferred outputs.
// Counter induction: entering t requires cnt >= 16t => all 16 WGs signaled
// step t-1 (each signals once per step after its publish-ack). Ring depth 4.
// Registers: ~108 VGPR + 128 weight regs ~ 236/wave; at 4 waves/SIMD the
// 512/wave budget holds (no spill).
__global__ __launch_bounds__(1024, 1) void lstm_rec(
    const u16* __restrict__ whh,   // [4096][1024] bf16
    const u16* __restrict__ xg,    // [64*512][4096] bf16 (row b*512+t), bias included
    u16* __restrict__ hx,          // [4][4][32][64][8] bf16 (fragment order)
    int* cnt,                      // [4*64] (256B-spaced per group)
    float* __restrict__ hs,
    float* __restrict__ cs)
{
  __shared__ u16 lds_h[16384];     // 32 KiB: group h in fragment order [32][64][8]
  const int tid  = threadIdx.x;
  const int lane = tid & 63;
  const int w    = tid >> 6;          // wave 0..15
  const int bid  = blockIdx.x;
  const int g    = bid >> 4;          // batch group 0..3
  const int j    = bid & 15;          // col-slice 0..15
  const int q    = (lane & 15) >> 2;  // gate type 0:i 1:f 2:g 3:o
  const int col  = j*64 + w*4 + (lane & 3);   // h column 0..1023
  const int Gr   = q*1024 + col;              // gate row 0..4095
  const int mloc = (lane >> 4) * 4;           // batch-in-group base

  // ---- weights -> regs (R6-proven; compiler parks them in AGPRs) ----
  i32x4 wq[32];
  {
    const i32x4* wp = (const i32x4*)(whh + (size_t)Gr*1024 + ((lane>>4)*8));
#pragma unroll
    for (int kk = 0; kk < 32; kk++) wq[kk] = wp[kk*4];
#pragma unroll
    for (int kk = 0; kk < 32; kk++) asm volatile("" : "+v"(wq[kk]));
  }

  float c_st[4] = {0.f,0.f,0.f,0.f};
  int* cntg = cnt + g*64;

  for (int t = 0; t < NT; t++){
    // xg prefetch: raw u16 loads issued BEFORE the poll (fly during detect);
    // converted after the stage barrier.
    u16 xraw[4];
#pragma unroll
    for (int reg = 0; reg < 4; reg++){
      int b = g*16 + mloc + reg;
      xraw[reg] = xg[((size_t)b*NT + t)*G4H + Gr];
    }
    // ---- wait for h(t-1): leader relaxed poll -> barrier (R14, ALWAYS) ----
    if (t > 0){
      if (tid == 0){
        const int need = t * 16;
        while (__hip_atomic_load(cntg, __ATOMIC_RELAXED, __HIP_MEMORY_SCOPE_AGENT) < need)
          __builtin_amdgcn_s_sleep(1);
      }
      __syncthreads();
    }
    // ---- stage h(t-1) -> LDS via sc1 atomic u64 loads (bypass stale L2) ----
    const u64* hb64 = (const u64*)(hx + ((size_t)(((t+3)&3)*4 + g)) * 16384);
#pragma unroll
    for (int k = 0; k < 4; k++){
      int W = tid + 1024*k;
      u64 v = __hip_atomic_load(hb64 + W, __ATOMIC_RELAXED, __HIP_MEMORY_SCOPE_AGENT);
      *(u64*)&lds_h[W*4] = v;
    }
    __syncthreads();

    // ---- gates = xg + h @ w_hh^T : 32 builtin MFMAs ----
    f32x4 accv[4];
    accv[0] = (f32x4){bf2f(xraw[0]), bf2f(xraw[1]), bf2f(xraw[2]), bf2f(xraw[3])};
    accv[1] = (f32x4){0.f,0.f,0.f,0.f};
    accv[2] = accv[1]; accv[3] = accv[1];
#pragma unroll
    for (int kk = 0; kk < 32; kk++){
      short8 av = *(const short8*)&lds_h[(kk*64 + lane)*8];
      short8 bv = __builtin_bit_cast(short8, wq[kk]);
      accv[kk & 3] = __builtin_amdgcn_mfma_f32_16x16x32_bf16(av, bv, accv[kk & 3], 0,0,0);
    }
    f32x4 gv = (accv[0] + accv[1]) + (accv[2] + accv[3]);

    // ---- activations; publish h, ack, signal, THEN deferred output stores ----
    u16* wbuf = hx + ((size_t)((t&3)*4 + g)) * 16384;
    float hnv[4], cnv[4];
#pragma unroll
    for (int reg = 0; reg < 4; reg++){
      float xg_ = gv[reg];
      float sig = 1.f / (1.f + __expf(-xg_));
      float th  = 1.f - 2.f / (1.f + __expf(2.f*xg_));
      float a   = (q == 2) ? th : sig;
      float v4  = __shfl_xor(a, 4);
      float v8  = __shfl_xor(a, 8);
      float v12 = __shfl_xor(a, 12);
      float iv  = (q==0)?a :(q==1)?v4:(q==2)?v8:v12;
      float fv  = (q==1)?a :(q==0)?v4:(q==3)?v8:v12;
      float gg  = (q==2)?a :(q==3)?v4:(q==0)?v8:v12;
      float ov  = (q==3)?a :(q==2)?v4:(q==1)?v8:v12;
      float cn  = fv*c_st[reg] + iv*gg;
      c_st[reg] = cn;
      float tc  = 1.f - 2.f / (1.f + __expf(2.f*cn));
      float hn  = ov * tc;
      hnv[reg] = hn; cnv[reg] = cn;
      // publish h via paired u32 sc1 atomic store (write-through to L3)
      float hp = __shfl_xor(hn, 1);          // partner column's h
      if (q == 0 && (lane & 1) == 0){
        unsigned word = (unsigned)f2bf(hn) | ((unsigned)f2bf(hp) << 16);
        int sub = ((col & 31) >> 3)*16 + (mloc + reg);
        int idx16 = ((col >> 5)*64 + sub)*8 + (col & 7);   // even
        __hip_atomic_store((unsigned*)(wbuf + idx16), word,
                           __ATOMIC_RELAXED, __HIP_MEMORY_SCOPE_AGENT);
      }
    }
    __syncthreads();   // drains ONLY the publish stores (outputs not yet issued)
    if (tid == 0)
      __hip_atomic_fetch_add(cntg, 1, __ATOMIC_RELAXED, __HIP_MEMORY_SCOPE_AGENT);
    // deferred output stores — off the signal path; acks drain next step
#pragma unroll
    for (int reg = 0; reg < 4; reg++){
      int b = g*16 + mloc + reg;
      size_t oidx = ((size_t)b*NT + t)*NH + col;
      if (q == 1) __builtin_nontemporal_store(hnv[reg], &hs[oidx]);
      if (q == 2) __builtin_nontemporal_store(cnv[reg], &cs[oidx]);
    }
  }
}

extern "C" void kernel_launch(void* const* d_in, const int* in_sizes, int n_in,
                              void* d_out, int out_size, void* d_ws, size_t ws_size,
                              hipStream_t stream){
  const float* x    = (const float*)d_in[0];
  const float* wih  = (const float*)d_in[1];
  const float* whh  = (const float*)d_in[2];
  const float* bias = (const float*)d_in[3];
  float* hs = (float*)d_out;
  float* cs = hs + HS_ELEMS;
  char* ws = (char*)d_ws;
  // ws layout (~337 MiB)
  u16* xg   = (u16*)(ws + 0);              // 256 MiB
  u16* xb   = (u16*)(ws + 268435456ull);   // 64 MiB
  u16* wihb = (u16*)(ws + 335544320ull);   // 8 MiB
  u16* whhb = (u16*)(ws + 343932928ull);   // 8 MiB
  u16* hx   = (u16*)(ws + 352321536ull);   // 512 KiB ring
  int* cnt  = (int*)(ws + 352845824ull);   // 1 KiB

  cvt_kernel<<<2048, 256, 0, stream>>>(x,   xb,   33554432/8);
  cvt_kernel<<<512,  256, 0, stream>>>(wih, wihb, 4194304/8);
  cvt_kernel<<<512,  256, 0, stream>>>(whh, whhb, 4194304/8);
  init_kernel<<<64,  256, 0, stream>>>((unsigned*)hx, cnt);
  gemm_xg<<<8192, 256, 0, stream>>>(xb, wihb, bias, xg);

  const u16* whhb_c = whhb; const u16* xg_c = xg;
  u16* hx_p = hx; int* cnt_p = cnt; float* hs_p = hs; float* cs_p = cs;
  void* args[6];
  args[0] = (void*)&whhb_c;
  args[1] = (void*)&xg_c;
  args[2] = (void*)&hx_p;
  args[3] = (void*)&cnt_p;
  args[4] = (void*)&hs_p;
  args[5] = (void*)&cs_p;
  hipLaunchCooperativeKernel((const void*)lstm_rec, dim3(64), dim3(1024), args, 0, stream);
}

// Round 19
// 3025.802 us; speedup vs baseline: 2.1314x; 2.1314x over previous
//
#include <hip/hip_runtime.h>
#include <stdint.h>

typedef unsigned short u16;
typedef short short8 __attribute__((ext_vector_type(8)));
typedef float f32x4 __attribute__((ext_vector_type(4)));
typedef int i32x4 __attribute__((ext_vector_type(4)));
typedef unsigned long long u64;

#define NT 512
#define NH 1024
#define G4H 4096
#define HS_ELEMS 33554432ull   // 64*512*1024

static __device__ __forceinline__ u16 f2bf(float f){
  union { float f; unsigned u; } v; v.f = f;
  unsigned r = v.u + 0x7fffu + ((v.u >> 16) & 1u);   // RNE
  return (u16)(r >> 16);
}
static __device__ __forceinline__ float bf2f(u16 s){
  union { unsigned u; float f; } v; v.u = ((unsigned)s) << 16;
  return v.f;
}

// ---------------- fp32 -> bf16 bulk convert ----------------
__global__ void cvt_kernel(const float* __restrict__ in, u16* __restrict__ out, int n8){
  int i = blockIdx.x*blockDim.x + threadIdx.x;
  int stride = gridDim.x*blockDim.x;
  for (; i < n8; i += stride){
    const float4* p = (const float4*)in;
    float4 a = p[2*i], b = p[2*i+1];
    short8 o;
    o[0]=(short)f2bf(a.x); o[1]=(short)f2bf(a.y); o[2]=(short)f2bf(a.z); o[3]=(short)f2bf(a.w);
    o[4]=(short)f2bf(b.x); o[5]=(short)f2bf(b.y); o[6]=(short)f2bf(b.z); o[7]=(short)f2bf(b.w);
    ((short8*)out)[i] = o;
  }
}

// ---------------- init h ring buffer + counters ----------------
__global__ void init_kernel(unsigned* __restrict__ hx, int* __restrict__ cnt){
  int i = blockIdx.x*blockDim.x + threadIdx.x;
  int stride = gridDim.x*blockDim.x;
  for (int k = i; k < 131072; k += stride) hx[k] = 0u;   // 512 KiB of bf16 zeros
  if (i < 256) cnt[i] = 0;
}

// ---------------- phase 1: xg = x @ w_ih^T + b  (bf16 MFMA, m97-style) ----------------
__global__ __launch_bounds__(256) void gemm_xg(
    const u16* __restrict__ A,     // x bf16 [32768][1024]
    const u16* __restrict__ Bw,    // w_ih bf16 [4096][1024]  (B^T layout)
    const float* __restrict__ bias,
    u16* __restrict__ C)           // xg bf16 [32768][4096]
{
  __shared__ u16 lA[128*64];
  __shared__ u16 lB[128*64];
  const int tid = threadIdx.x, lane = tid & 63, w = tid >> 6;
  int bid = blockIdx.x;
  int swz = (bid & 7)*1024 + (bid >> 3);     // XCD swizzle (8192 % 8 == 0, bijective)
  const int brow = swz >> 5;                 // 0..255
  const int bcol = swz & 31;                 // 0..31
  const int wr = (w >> 1)*64, wc = (w & 1)*64;
  f32x4 acc[4][4] = {};

  const int rA0 = brow*128 + w*32;
  const int rB0 = bcol*128 + w*32;
  for (int kt = 0; kt < 1024; kt += 64){
    const u16* gA = A  + (size_t)(rA0 + (lane>>3))*1024 + kt + (lane&7)*8;
    const u16* gB = Bw + (size_t)(rB0 + (lane>>3))*1024 + kt + (lane&7)*8;
#pragma unroll
    for (int c = 0; c < 4; c++){
      __builtin_amdgcn_global_load_lds(
        (const __attribute__((address_space(1))) void*)(gA + (size_t)c*8*1024),
        (__attribute__((address_space(3))) void*)&lA[(w*32 + c*8)*64], 16, 0, 0);
      __builtin_amdgcn_global_load_lds(
        (const __attribute__((address_space(1))) void*)(gB + (size_t)c*8*1024),
        (__attribute__((address_space(3))) void*)&lB[(w*32 + c*8)*64], 16, 0, 0);
    }
    __syncthreads();
#pragma unroll
    for (int kk = 0; kk < 2; kk++){
      short8 fa[4], fb[4];
#pragma unroll
      for (int i = 0; i < 4; i++){
        fa[i] = *(const short8*)&lA[(wr + i*16 + (lane&15))*64 + kk*32 + (lane>>4)*8];
        fb[i] = *(const short8*)&lB[(wc + i*16 + (lane&15))*64 + kk*32 + (lane>>4)*8];
      }
#pragma unroll
      for (int i = 0; i < 4; i++)
#pragma unroll
        for (int jj = 0; jj < 4; jj++)
          acc[i][jj] = __builtin_amdgcn_mfma_f32_16x16x32_bf16(fa[i], fb[jj], acc[i][jj], 0,0,0);
    }
    __syncthreads();
  }
  const int mb = brow*128 + wr + ((lane>>4)<<2);
  const int nb = bcol*128 + wc + (lane&15);
#pragma unroll
  for (int jj = 0; jj < 4; jj++){
    const int n = nb + jj*16;
    const float bv = bias[n];
#pragma unroll
    for (int i = 0; i < 4; i++){
#pragma unroll
      for (int reg = 0; reg < 4; reg++){
        int m = mb + i*16 + reg;
        C[(size_t)m*G4H + n] = f2bf(acc[i][jj][reg] + bv);
      }
    }
  }
}

// ---------------- phase 2: persistent recurrence (R14 protocol, 32 WGs/group) ----------------
// Grid 128 x 512 threads = 4 batch-groups x 32 col-slice WGs (32 h-cols each,
// 8 waves). vs R14's 64 WGs/group: signals/step halved, straggler pool
// max-of-32 not max-of-64, publish-ack aggregated over 8 waves per intra-WG
// barrier, stage traffic halved. __launch_bounds__(512,2) -> 2 waves/SIMD ->
// 256 VGPR/wave budget; 128 weight regs + ~108 working = ~236 FITS (the R18
// lesson: 1024-thread WG capped the budget at 128 and killed residency).
// Protocol ordering BYTE-IDENTICAL to R14/R17 (PASSED, 3.36ms):
//   reader: tid0 relaxed poll (cnt >= 32t) -> barrier -> sc1 stage -> LDS ->
//           barrier; writer: publish sc1 u32 pairs -> barrier (ack) -> tid0
//           relaxed fetch_add -> deferred hs/cs stores.
// Counter induction: entering t requires cnt >= 32t => all 32 WGs signaled
// step t-1. Ring depth 4 => race-free.
__global__ __launch_bounds__(512, 2) void lstm_rec(
    const u16* __restrict__ whh,   // [4096][1024] bf16
    const u16* __restrict__ xg,    // [64*512][4096] bf16 (row b*512+t), bias included
    u16* __restrict__ hx,          // [4][4][32][64][8] bf16 (fragment order)
    int* cnt,                      // [4*64] (256B-spaced per group)
    float* __restrict__ hs,
    float* __restrict__ cs)
{
  __shared__ u16 lds_h[16384];     // 32 KiB: group h in fragment order [32][64][8]
  const int tid  = threadIdx.x;
  const int lane = tid & 63;
  const int w    = tid >> 6;          // wave 0..7
  const int bid  = blockIdx.x;
  const int g    = bid >> 5;          // batch group 0..3
  const int j    = bid & 31;          // col-slice 0..31
  const int q    = (lane & 15) >> 2;  // gate type 0:i 1:f 2:g 3:o
  const int col  = j*32 + w*4 + (lane & 3);   // h column 0..1023
  const int Gr   = q*1024 + col;              // gate row 0..4095
  const int mloc = (lane >> 4) * 4;           // batch-in-group base

  // ---- weights -> regs (R6-proven; compiler parks them in AGPRs) ----
  i32x4 wq[32];
  {
    const i32x4* wp = (const i32x4*)(whh + (size_t)Gr*1024 + ((lane>>4)*8));
#pragma unroll
    for (int kk = 0; kk < 32; kk++) wq[kk] = wp[kk*4];
#pragma unroll
    for (int kk = 0; kk < 32; kk++) asm volatile("" : "+v"(wq[kk]));
  }

  float c_st[4] = {0.f,0.f,0.f,0.f};
  int* cntg = cnt + g*64;

  for (int t = 0; t < NT; t++){
    // xg prefetch (independent of h) — hides HBM latency under the poll
    float xv[4];
#pragma unroll
    for (int reg = 0; reg < 4; reg++){
      int b = g*16 + mloc + reg;
      xv[reg] = bf2f(xg[((size_t)b*NT + t)*G4H + Gr]);
    }
    // ---- wait for h(t-1): leader relaxed poll -> barrier (R14, ALWAYS) ----
    if (t > 0){
      if (tid == 0){
        const int need = t * 32;
        while (__hip_atomic_load(cntg, __ATOMIC_RELAXED, __HIP_MEMORY_SCOPE_AGENT) < need)
          __builtin_amdgcn_s_sleep(1);
      }
      __syncthreads();
    }
    // ---- stage h(t-1) -> LDS via sc1 atomic u64 loads (bypass stale L2) ----
    const u64* hb64 = (const u64*)(hx + ((size_t)(((t+3)&3)*4 + g)) * 16384);
#pragma unroll
    for (int k = 0; k < 8; k++){
      int W = tid + 512*k;
      u64 v = __hip_atomic_load(hb64 + W, __ATOMIC_RELAXED, __HIP_MEMORY_SCOPE_AGENT);
      *(u64*)&lds_h[W*4] = v;
    }
    __syncthreads();

    // ---- gates = xg + h @ w_hh^T : 32 builtin MFMAs ----
    f32x4 accv[4];
    accv[0] = (f32x4){xv[0], xv[1], xv[2], xv[3]};
    accv[1] = (f32x4){0.f,0.f,0.f,0.f};
    accv[2] = accv[1]; accv[3] = accv[1];
#pragma unroll
    for (int kk = 0; kk < 32; kk++){
      short8 av = *(const short8*)&lds_h[(kk*64 + lane)*8];
      short8 bv = __builtin_bit_cast(short8, wq[kk]);
      accv[kk & 3] = __builtin_amdgcn_mfma_f32_16x16x32_bf16(av, bv, accv[kk & 3], 0,0,0);
    }
    f32x4 gv = (accv[0] + accv[1]) + (accv[2] + accv[3]);

    // ---- activations; publish h, ack, signal, THEN deferred output stores ----
    u16* wbuf = hx + ((size_t)((t&3)*4 + g)) * 16384;
    float hnv[4], cnv[4];
#pragma unroll
    for (int reg = 0; reg < 4; reg++){
      float xg_ = gv[reg];
      float sig = 1.f / (1.f + __expf(-xg_));
      float th  = 1.f - 2.f / (1.f + __expf(2.f*xg_));
      float a   = (q == 2) ? th : sig;
      float v4  = __shfl_xor(a, 4);
      float v8  = __shfl_xor(a, 8);
      float v12 = __shfl_xor(a, 12);
      float iv  = (q==0)?a :(q==1)?v4:(q==2)?v8:v12;
      float fv  = (q==1)?a :(q==0)?v4:(q==3)?v8:v12;
      float gg  = (q==2)?a :(q==3)?v4:(q==0)?v8:v12;
      float ov  = (q==3)?a :(q==2)?v4:(q==1)?v8:v12;
      float cn  = fv*c_st[reg] + iv*gg;
      c_st[reg] = cn;
      float tc  = 1.f - 2.f / (1.f + __expf(2.f*cn));
      float hn  = ov * tc;
      hnv[reg] = hn; cnv[reg] = cn;
      // publish h via paired u32 sc1 atomic store (write-through to L3)
      float hp = __shfl_xor(hn, 1);          // partner column's h
      if (q == 0 && (lane & 1) == 0){
        unsigned word = (unsigned)f2bf(hn) | ((unsigned)f2bf(hp) << 16);
        int sub = ((col & 31) >> 3)*16 + (mloc + reg);
        int idx16 = ((col >> 5)*64 + sub)*8 + (col & 7);   // even
        __hip_atomic_store((unsigned*)(wbuf + idx16), word,
                           __ATOMIC_RELAXED, __HIP_MEMORY_SCOPE_AGENT);
      }
    }
    __syncthreads();   // drains ONLY the publish stores (outputs not yet issued)
    if (tid == 0)
      __hip_atomic_fetch_add(cntg, 1, __ATOMIC_RELAXED, __HIP_MEMORY_SCOPE_AGENT);
    // deferred output stores — off the signal path; acks drain next step
#pragma unroll
    for (int reg = 0; reg < 4; reg++){
      int b = g*16 + mloc + reg;
      size_t oidx = ((size_t)b*NT + t)*NH + col;
      if (q == 1) __builtin_nontemporal_store(hnv[reg], &hs[oidx]);
      if (q == 2) __builtin_nontemporal_store(cnv[reg], &cs[oidx]);
    }
  }
}

extern "C" void kernel_launch(void* const* d_in, const int* in_sizes, int n_in,
                              void* d_out, int out_size, void* d_ws, size_t ws_size,
                              hipStream_t stream){
  const float* x    = (const float*)d_in[0];
  const float* wih  = (const float*)d_in[1];
  const float* whh  = (const float*)d_in[2];
  const float* bias = (const float*)d_in[3];
  float* hs = (float*)d_out;
  float* cs = hs + HS_ELEMS;
  char* ws = (char*)d_ws;
  // ws layout (~337 MiB)
  u16* xg   = (u16*)(ws + 0);              // 256 MiB
  u16* xb   = (u16*)(ws + 268435456ull);   // 64 MiB
  u16* wihb = (u16*)(ws + 335544320ull);   // 8 MiB
  u16* whhb = (u16*)(ws + 343932928ull);   // 8 MiB
  u16* hx   = (u16*)(ws + 352321536ull);   // 512 KiB ring
  int* cnt  = (int*)(ws + 352845824ull);   // 1 KiB

  cvt_kernel<<<2048, 256, 0, stream>>>(x,   xb,   33554432/8);
  cvt_kernel<<<512,  256, 0, stream>>>(wih, wihb, 4194304/8);
  cvt_kernel<<<512,  256, 0, stream>>>(whh, whhb, 4194304/8);
  init_kernel<<<64,  256, 0, stream>>>((unsigned*)hx, cnt);
  gemm_xg<<<8192, 256, 0, stream>>>(xb, wihb, bias, xg);

  const u16* whhb_c = whhb; const u16* xg_c = xg;
  u16* hx_p = hx; int* cnt_p = cnt; float* hs_p = hs; float* cs_p = cs;
  void* args[6];
  args[0] = (void*)&whhb_c;
  args[1] = (void*)&xg_c;
  args[2] = (void*)&hx_p;
  args[3] = (void*)&cnt_p;
  args[4] = (void*)&hs_p;
  args[5] = (void*)&cs_p;
  hipLaunchCooperativeKernel((const void*)lstm_rec, dim3(128), dim3(512), args, 0, stream);
}